// Round 5
// baseline (628.695 us; speedup 1.0000x reference)
//
#include <hip/hip_runtime.h>
#include <hip/hip_bf16.h>

typedef __attribute__((ext_vector_type(8))) short short8;
typedef __attribute__((ext_vector_type(4))) float f32x4;

#define MFMA16(a, b, c) __builtin_amdgcn_mfma_f32_16x16x32_bf16((a), (b), (c), 0, 0, 0)

__device__ __forceinline__ unsigned short f2bf(float x) {
    union { float f; unsigned int u; } v; v.f = x;
    unsigned int u = v.u;
    return (unsigned short)((u + 0x7FFFu + ((u >> 16) & 1u)) >> 16);
}

__device__ __forceinline__ short8 ld8(const unsigned short* p) {
    return *reinterpret_cast<const short8*>(p);
}

// ---- K0: bbn fp32 -> bf16, row sums s[i] (fp32) ------------------------------
__global__ void k_prep_bbn(const float* __restrict__ bbn, unsigned short* __restrict__ bbn_h,
                           float* __restrict__ s) {
    int row = blockIdx.x * 4 + (threadIdx.x >> 6);
    int lane = threadIdx.x & 63;
    float x = bbn[row * 64 + lane];
    bbn_h[row * 64 + lane] = f2bf(x);
    float v = x;
    #pragma unroll
    for (int m = 1; m < 64; m <<= 1) v += __shfl_xor(v, m);
    if (lane == 0) s[row] = v;
}

// ---- K0b/K2: transpose (+optional rsqrt(d) row scale), fp32 -> bf16 ----------
__global__ void k_transpose_scale(const float* __restrict__ in, unsigned short* __restrict__ out,
                                  const float* __restrict__ dvec, int K, int N) {
    __shared__ float tile[64][65];
    int tiles_k = K >> 6;
    int tk = blockIdx.x % tiles_k, tn = blockIdx.x / tiles_k;
    int k0 = tk * 64, n0 = tn * 64;
    int c = threadIdx.x & 63, rq = threadIdx.x >> 6;
    #pragma unroll
    for (int i = 0; i < 16; ++i) {
        int r = rq + 4 * i;
        float sc = dvec ? rsqrtf(dvec[k0 + r]) : 1.0f;
        tile[r][c] = in[(size_t)(k0 + r) * N + n0 + c] * sc;
    }
    __syncthreads();
    #pragma unroll
    for (int i = 0; i < 16; ++i) {
        int r = rq + 4 * i;
        out[(size_t)(n0 + r) * K + k0 + c] = f2bf(tile[c][r]);
    }
}

// ---- K1: degree d[i] = sum_j (1 - |2*G_ij - s_i - s_j|/64)^1.4 ---------------
__global__ __launch_bounds__(512) void k_degree(const unsigned short* __restrict__ bbn_h,
                                                const float* __restrict__ s,
                                                float* __restrict__ d) {
    int i0 = blockIdx.x * 16;
    int tid = threadIdx.x;
    int w = tid >> 6, l = tid & 63, g = l >> 4, c = l & 15;

    const unsigned short* ap = bbn_h + (i0 + c) * 64;
    short8 a0 = ld8(ap);
    short8 a1 = ld8(ap + 32);
    f32x4 si4 = *reinterpret_cast<const f32x4*>(s + i0 + g * 4);

    float acc[4] = {0.f, 0.f, 0.f, 0.f};
    #pragma unroll 4
    for (int j0 = w * 16; j0 < 8192; j0 += 128) {
        int jrow = j0 + c;
        const unsigned short* bp = bbn_h + jrow * 64;
        short8 b0 = ld8(bp);
        short8 b1 = ld8(bp + 32);
        float sj = s[jrow];
        f32x4 gf = {0.f, 0.f, 0.f, 0.f};
        gf = MFMA16(a0, b0, gf);
        gf = MFMA16(a1, b1, gf);
        #pragma unroll
        for (int r = 0; r < 4; ++r) {
            float t = fmaf(2.f, gf[r], -(si4[r] + sj));
            float x = fmaf(fabsf(t), -0.015625f, 1.f);
            x = fmaxf(x, 0.f);
            acc[r] += exp2f(1.4f * log2f(x));
        }
    }

    __shared__ float part[8][16];
    #pragma unroll
    for (int r = 0; r < 4; ++r) {
        float v = acc[r];
        v += __shfl_xor(v, 1); v += __shfl_xor(v, 2);
        v += __shfl_xor(v, 4); v += __shfl_xor(v, 8);
        if (c == 0) part[w][g * 4 + r] = v;
    }
    __syncthreads();
    if (tid < 16) {
        float v = 0.f;
        #pragma unroll
        for (int ww = 0; ww < 8; ++ww) v += part[ww][tid];
        d[i0 + tid] = v;
    }
}

// ---- K3: fused h = D^-1/2 A D^-1/2 cbn ---------------------------------------
// BM=64, BN=128, BK=64; 512 threads (8 waves, wave grid 2x4 -> 32x32/wave).
// 512 blocks = 2 blocks/CU: inter-block overlap hides the barrier drain.
// Gen: 8 waves x two 16x16 subtiles, swapped MFMA -> packed ds_write_b64.
// t+2 register pipeline for gen loads; ONE barrier/iter; A-LDS double-buffered.
__global__ __launch_bounds__(512, 4) void k_spectral(const unsigned short* __restrict__ bbn_h,
                                                     const float* __restrict__ s,
                                                     const float* __restrict__ d,
                                                     const unsigned short* __restrict__ cbn_sT,
                                                     unsigned short* __restrict__ h) {
    int bx = blockIdx.x;
    // 8 XCDs: XCD x serves col-tile x&3 (2MB slab + 1MB bbn_h fits 4MB L2);
    // row-tiles split: XCDs 0-3 rows 0..63, XCDs 4-7 rows 64..127.
    int xcd = bx & 7, idx = bx >> 3;          // idx 0..63
    int i0 = (idx + ((xcd >> 2) << 6)) * 64;  // 128 row-tiles
    int n0 = (xcd & 3) * 128;                 // 4 col-tiles

    int tid = threadIdx.x;
    int w = tid >> 6, l = tid & 63, g = l >> 4, c = l & 15;
    int wm = w >> 2, wn = w & 3;        // main: rows wm*32, cols wn*32
    int gi = w & 3, gjp = (w >> 2) * 2; // gen: i-subtile gi, j-subtiles gjp+{0,1}

    const unsigned short* ap = bbn_h + (i0 + gi * 16 + c) * 64;
    short8 ga0 = ld8(ap), ga1 = ld8(ap + 32);
    float si = s[i0 + gi * 16 + c];

    __shared__ unsigned char Alds0[8192];
    __shared__ unsigned char Alds1[8192];

    f32x4 acc[2][2] = {};

    const unsigned short* gb0 = bbn_h + ((gjp + 0) * 16 + c) * 64;  // + j*64
    const unsigned short* gb1 = bbn_h + ((gjp + 1) * 16 + c) * 64;
    const float* sb0 = s + (gjp + 0) * 16 + g * 4;                  // + j
    const float* sb1 = s + (gjp + 1) * 16 + g * 4;
    const int wr_bo0 = ((gi * 16 + c) * 128 + ((gjp + 0) * 16 + g * 4) * 2) ^ ((c & 7) << 4);
    const int wr_bo1 = ((gi * 16 + c) * 128 + ((gjp + 1) * 16 + g * 4) * 2) ^ ((c & 7) << 4);
    const unsigned short* bfr_base = cbn_sT + (size_t)(n0 + wn * 32 + c) * 8192 + g * 8;
    const int rd_row = wm * 32 + c;

    // prologue: gen tile 0 synchronously into Alds0
    {
        #pragma unroll
        for (int p = 0; p < 2; ++p) {
            const unsigned short* gbp = p ? gb1 : gb0;
            const float* sbp = p ? sb1 : sb0;
            short8 b0 = ld8(gbp), b1 = ld8(gbp + 32);
            f32x4 sj4 = *reinterpret_cast<const f32x4*>(sbp);
            f32x4 gf = {0.f, 0.f, 0.f, 0.f};
            gf = MFMA16(b0, ga0, gf);
            gf = MFMA16(b1, ga1, gf);
            unsigned short u[4];
            #pragma unroll
            for (int r = 0; r < 4; ++r) {
                float t = fmaf(2.f, gf[r], -(si + sj4[r]));
                float x = fmaxf(fmaf(fabsf(t), -0.015625f, 1.f), 0.f);
                u[r] = f2bf(exp2f(1.4f * log2f(x)));
            }
            *reinterpret_cast<uint2*>(&Alds0[p ? wr_bo1 : wr_bo0]) =
                make_uint2((unsigned)u[0] | ((unsigned)u[1] << 16),
                           (unsigned)u[2] | ((unsigned)u[3] << 16));
        }
    }
    // issue gen loads for tile 1 (consumed at iter 0's gen-compute)
    short8 bA[2][2]; f32x4 sA[2];
    bA[0][0] = ld8(gb0 + 64 * 64); bA[0][1] = ld8(gb0 + 64 * 64 + 32);
    bA[1][0] = ld8(gb1 + 64 * 64); bA[1][1] = ld8(gb1 + 64 * 64 + 32);
    sA[0] = *reinterpret_cast<const f32x4*>(sb0 + 64);
    sA[1] = *reinterpret_cast<const f32x4*>(sb1 + 64);
    short8 bB[2][2]; f32x4 sB[2];
    __syncthreads();

#define SPEC_ITER(T, LR, LW, bc, sc, bn, sn) do {                                   \
    const int j0_ = (T) << 6;                                                       \
    const int jn_ = ((T) + 2 < 128) ? (j0_ + 128) : 0;                              \
    bn[0][0] = ld8(gb0 + jn_ * 64); bn[0][1] = ld8(gb0 + jn_ * 64 + 32);            \
    bn[1][0] = ld8(gb1 + jn_ * 64); bn[1][1] = ld8(gb1 + jn_ * 64 + 32);            \
    sn[0] = *reinterpret_cast<const f32x4*>(sb0 + jn_);                             \
    sn[1] = *reinterpret_cast<const f32x4*>(sb1 + jn_);                             \
    short8 bfr_[2][2];                                                              \
    _Pragma("unroll")                                                               \
    for (int kk = 0; kk < 2; ++kk)                                                  \
        _Pragma("unroll")                                                           \
        for (int nn = 0; nn < 2; ++nn)                                              \
            bfr_[kk][nn] = ld8(bfr_base + (size_t)nn * 16 * 8192 + j0_ + kk * 32);  \
    short8 af_[2][2];                                                               \
    _Pragma("unroll")                                                               \
    for (int mi = 0; mi < 2; ++mi)                                                  \
        _Pragma("unroll")                                                           \
        for (int kk = 0; kk < 2; ++kk) {                                            \
            int bo_ = ((rd_row + mi * 16) * 128 + kk * 64 + g * 16) ^ ((c & 7) << 4); \
            af_[mi][kk] = *reinterpret_cast<const short8*>(&(LR)[bo_]);             \
        }                                                                           \
    if ((T) < 127) {  /* gen tile T+1 from regs loaded last iter */                 \
        _Pragma("unroll")                                                           \
        for (int p = 0; p < 2; ++p) {                                               \
            f32x4 gf_ = {0.f, 0.f, 0.f, 0.f};                                       \
            gf_ = MFMA16(bc[p][0], ga0, gf_);                                       \
            gf_ = MFMA16(bc[p][1], ga1, gf_);                                       \
            unsigned short u_[4];                                                   \
            _Pragma("unroll")                                                       \
            for (int r = 0; r < 4; ++r) {                                           \
                float t_ = fmaf(2.f, gf_[r], -(si + sc[p][r]));                     \
                float x_ = fmaxf(fmaf(fabsf(t_), -0.015625f, 1.f), 0.f);            \
                u_[r] = f2bf(exp2f(1.4f * log2f(x_)));                              \
            }                                                                       \
            *reinterpret_cast<uint2*>(&(LW)[p ? wr_bo1 : wr_bo0]) =                 \
                make_uint2((unsigned)u_[0] | ((unsigned)u_[1] << 16),               \
                           (unsigned)u_[2] | ((unsigned)u_[3] << 16));              \
        }                                                                           \
    }                                                                               \
    __builtin_amdgcn_s_setprio(1);                                                  \
    _Pragma("unroll")                                                               \
    for (int kk = 0; kk < 2; ++kk)                                                  \
        _Pragma("unroll")                                                           \
        for (int nn = 0; nn < 2; ++nn) {                                            \
            acc[0][nn] = MFMA16(af_[0][kk], bfr_[kk][nn], acc[0][nn]);              \
            acc[1][nn] = MFMA16(af_[1][kk], bfr_[kk][nn], acc[1][nn]);              \
        }                                                                           \
    __builtin_amdgcn_s_setprio(0);                                                  \
    __syncthreads();                                                                \
} while (0)

    for (int t2 = 0; t2 < 64; ++t2) {
        SPEC_ITER(2 * t2,     Alds0, Alds1, bA, sA, bB, sB);
        SPEC_ITER(2 * t2 + 1, Alds1, Alds0, bB, sB, bA, sA);
    }
#undef SPEC_ITER

    // epilogue: scale by dinv_i, store bf16 h
    #pragma unroll
    for (int mi = 0; mi < 2; ++mi) {
        f32x4 d4 = *reinterpret_cast<const f32x4*>(d + i0 + wm * 32 + mi * 16 + g * 4);
        #pragma unroll
        for (int r = 0; r < 4; ++r) {
            int row = i0 + wm * 32 + mi * 16 + g * 4 + r;
            float dinv = rsqrtf(d4[r]);
            #pragma unroll
            for (int nn = 0; nn < 2; ++nn)
                h[(size_t)row * 512 + n0 + wn * 32 + nn * 16 + c] = f2bf(acc[mi][nn][r] * dinv);
        }
    }
}

// ---- K4: out = sigmoid(h @ W + b), fp32 out ----------------------------------
// 512 blocks: 256 row-tiles (32 rows) x 2 col-tiles (256 cols); 8 waves 2x4
__global__ __launch_bounds__(512) void k_out(const unsigned short* __restrict__ h,
                                             const unsigned short* __restrict__ Wt,
                                             const float* __restrict__ b,
                                             float* __restrict__ out) {
    int bx = blockIdx.x;
    int i0 = (bx & 255) * 32, n0 = (bx >> 8) * 256;
    int tid = threadIdx.x;
    int w = tid >> 6, l = tid & 63, g = l >> 4, c = l & 15;
    int wm = w >> 2, wn = w & 3;   // rows wm*16, cols wn*64

    float bb[4];
    #pragma unroll
    for (int nn = 0; nn < 4; ++nn) bb[nn] = b[n0 + wn * 64 + nn * 16 + c];

    f32x4 acc[4] = {};
    for (int k0 = 0; k0 < 512; k0 += 64) {
        short8 af[2];
        #pragma unroll
        for (int kk = 0; kk < 2; ++kk)
            af[kk] = ld8(h + (size_t)(i0 + wm * 16 + c) * 512 + k0 + kk * 32 + g * 8);
        #pragma unroll
        for (int kk = 0; kk < 2; ++kk)
            #pragma unroll
            for (int nn = 0; nn < 4; ++nn) {
                short8 bf = ld8(Wt + (size_t)(n0 + wn * 64 + nn * 16 + c) * 512 + k0 + kk * 32 + g * 8);
                acc[nn] = MFMA16(af[kk], bf, acc[nn]);
            }
    }
    #pragma unroll
    for (int r = 0; r < 4; ++r) {
        int row = i0 + wm * 16 + g * 4 + r;
        #pragma unroll
        for (int nn = 0; nn < 4; ++nn) {
            float z = acc[nn][r] + bb[nn];
            out[(size_t)row * 512 + n0 + wn * 64 + nn * 16 + c] = 1.f / (1.f + exp2f(-1.44269504f * z));
        }
    }
}

extern "C" void kernel_launch(void* const* d_in, const int* in_sizes, int n_in,
                              void* d_out, int out_size, void* d_ws, size_t ws_size,
                              hipStream_t stream) {
    const float* bbn = (const float*)d_in[0];   // [8192, 64]
    const float* cbn = (const float*)d_in[1];   // [8192, 512]
    const float* W   = (const float*)d_in[2];   // [512, 512]
    const float* b   = (const float*)d_in[3];   // [512]
    float* out = (float*)d_out;                 // [8192, 512] fp32

    char* ws = (char*)d_ws;
    unsigned short* bbn_h  = (unsigned short*)(ws);                    // 1 MB
    float*          s      = (float*)(ws + (1u << 20));                // 32 KB
    float*          dd     = (float*)(ws + (1u << 20) + (1u << 15));   // 32 KB
    unsigned short* Wt     = (unsigned short*)(ws + (1u << 20) + (2u << 15));           // 512 KB
    unsigned short* cbn_sT = (unsigned short*)(ws + (1u << 20) + (2u << 15) + (1u << 19));        // 8 MB
    unsigned short* hbuf   = (unsigned short*)(ws + (1u << 20) + (2u << 15) + (1u << 19) + (1u << 23)); // 8 MB

    k_prep_bbn<<<2048, 256, 0, stream>>>(bbn, bbn_h, s);
    k_transpose_scale<<<64, 256, 0, stream>>>(W, Wt, nullptr, 512, 512);
    k_degree<<<512, 512, 0, stream>>>(bbn_h, s, dd);
    k_transpose_scale<<<1024, 256, 0, stream>>>(cbn, cbn_sT, dd, 8192, 512);
    k_spectral<<<512, 512, 0, stream>>>(bbn_h, s, dd, cbn_sT, hbuf);
    k_out<<<512, 512, 0, stream>>>(hbuf, Wt, b, out);
}

// Round 8
// 505.205 us; speedup vs baseline: 1.2444x; 1.2444x over previous
//
#include <hip/hip_runtime.h>
#include <hip/hip_bf16.h>

typedef __attribute__((ext_vector_type(8))) short short8;
typedef __attribute__((ext_vector_type(4))) float f32x4;

#define MFMA16(a, b, c) __builtin_amdgcn_mfma_f32_16x16x32_bf16((a), (b), (c), 0, 0, 0)

// fused wait+barrier: memory clobber fences BOTH sides; no vmcnt drain so
// global prefetch loads stay in flight across the barrier.
#define BARRIER_LGKM() asm volatile("s_waitcnt lgkmcnt(0)\ns_barrier" ::: "memory")

__device__ __forceinline__ unsigned short f2bf(float x) {
    union { float f; unsigned int u; } v; v.f = x;
    unsigned int u = v.u;
    return (unsigned short)((u + 0x7FFFu + ((u >> 16) & 1u)) >> 16);
}

// r4-proven numerics: libm exp2f/log2f (r6/r7's raw-builtin path failed absmax)
__device__ __forceinline__ float pow14(float x) {
    return exp2f(1.4f * log2f(x));
}

__device__ __forceinline__ short8 ld8(const unsigned short* p) {
    return *reinterpret_cast<const short8*>(p);
}

// ---- K0: bbn fp32 -> bf16, row sums s[i] (fp32) ------------------------------
__global__ void k_prep_bbn(const float* __restrict__ bbn, unsigned short* __restrict__ bbn_h,
                           float* __restrict__ s) {
    int row = blockIdx.x * 4 + (threadIdx.x >> 6);
    int lane = threadIdx.x & 63;
    float x = bbn[row * 64 + lane];
    bbn_h[row * 64 + lane] = f2bf(x);
    float v = x;
    #pragma unroll
    for (int m = 1; m < 64; m <<= 1) v += __shfl_xor(v, m);
    if (lane == 0) s[row] = v;
}

// ---- K0b/K2: transpose (+optional rsqrt(d) row scale), fp32 -> bf16 ----------
__global__ void k_transpose_scale(const float* __restrict__ in, unsigned short* __restrict__ out,
                                  const float* __restrict__ dvec, int K, int N) {
    __shared__ float tile[64][65];
    int tiles_k = K >> 6;
    int tk = blockIdx.x % tiles_k, tn = blockIdx.x / tiles_k;
    int k0 = tk * 64, n0 = tn * 64;
    int c = threadIdx.x & 63, rq = threadIdx.x >> 6;
    #pragma unroll
    for (int i = 0; i < 16; ++i) {
        int r = rq + 4 * i;
        float sc = dvec ? rsqrtf(dvec[k0 + r]) : 1.0f;
        tile[r][c] = in[(size_t)(k0 + r) * N + n0 + c] * sc;
    }
    __syncthreads();
    #pragma unroll
    for (int i = 0; i < 16; ++i) {
        int r = rq + 4 * i;
        out[(size_t)(n0 + r) * K + k0 + c] = f2bf(tile[c][r]);
    }
}

// ---- K1: degree d[i] = sum_j (1 - |2*G_ij - s_i - s_j|/64)^1.4 ---------------
__global__ __launch_bounds__(512) void k_degree(const unsigned short* __restrict__ bbn_h,
                                                const float* __restrict__ s,
                                                float* __restrict__ d) {
    int i0 = blockIdx.x * 16;
    int tid = threadIdx.x;
    int w = tid >> 6, l = tid & 63, g = l >> 4, c = l & 15;

    const unsigned short* ap = bbn_h + (i0 + c) * 64;
    short8 a0 = ld8(ap);
    short8 a1 = ld8(ap + 32);
    f32x4 si4 = *reinterpret_cast<const f32x4*>(s + i0 + g * 4);

    float acc[4] = {0.f, 0.f, 0.f, 0.f};
    #pragma unroll 4
    for (int j0 = w * 16; j0 < 8192; j0 += 128) {
        int jrow = j0 + c;
        const unsigned short* bp = bbn_h + jrow * 64;
        short8 b0 = ld8(bp);
        short8 b1 = ld8(bp + 32);
        float sj = s[jrow];
        f32x4 gf = {0.f, 0.f, 0.f, 0.f};
        gf = MFMA16(a0, b0, gf);
        gf = MFMA16(a1, b1, gf);
        #pragma unroll
        for (int r = 0; r < 4; ++r) {
            float t = fmaf(2.f, gf[r], -(si4[r] + sj));
            float x = fmaxf(fmaf(fabsf(t), -0.015625f, 1.f), 0.f);
            acc[r] += pow14(x);
        }
    }

    __shared__ float part[8][16];
    #pragma unroll
    for (int r = 0; r < 4; ++r) {
        float v = acc[r];
        v += __shfl_xor(v, 1); v += __shfl_xor(v, 2);
        v += __shfl_xor(v, 4); v += __shfl_xor(v, 8);
        if (c == 0) part[w][g * 4 + r] = v;
    }
    __syncthreads();
    if (tid < 16) {
        float v = 0.f;
        #pragma unroll
        for (int ww = 0; ww < 8; ++ww) v += part[ww][tid];
        d[i0 + tid] = v;
    }
}

// ---- K3: fused h = D^-1/2 A D^-1/2 cbn ---------------------------------------
// BM=64, BN=256, BK=64; 1024 threads (16 waves). Main: 2x8 waves, 32x32/wave.
// Gen: 16 waves x one 16x16 subtile, swapped MFMA -> packed ds_write_b64.
// t+2 register pipeline for gen loads; fused lgkmcnt(0)+s_barrier (no vmcnt
// drain). Numerics = r4-proven (libm trans, manual f2bf pack).
__global__ __launch_bounds__(1024, 4) void k_spectral(const unsigned short* __restrict__ bbn_h,
                                                      const float* __restrict__ s,
                                                      const float* __restrict__ d,
                                                      const unsigned short* __restrict__ cbn_sT,
                                                      unsigned short* __restrict__ h) {
    int bx = blockIdx.x;
    int xcd = bx & 7, hi = bx >> 3;
    int i0 = (hi * 4 + (xcd & 3)) * 64;
    int n0 = (xcd >> 2) * 256;

    int tid = threadIdx.x;
    int w = tid >> 6, l = tid & 63, g = l >> 4, c = l & 15;
    int wm = w >> 3, wn = w & 7;      // main wave tile: rows wm*32, cols wn*32
    int gi = w & 3, gj = w >> 2;      // gen subtile: i-rows gi*16, j-rows gj*16

    const unsigned short* ap = bbn_h + (i0 + gi * 16 + c) * 64;
    short8 ga0 = ld8(ap), ga1 = ld8(ap + 32);
    float si = s[i0 + gi * 16 + c];

    __shared__ unsigned char Alds0[8192];
    __shared__ unsigned char Alds1[8192];

    f32x4 acc[2][2] = {};

    const unsigned short* gb = bbn_h + (gj * 16 + c) * 64;   // + j*64
    const float* sb = s + gj * 16 + g * 4;                   // + j
    const int wr_bo = ((gi * 16 + c) * 128 + (gj * 16 + g * 4) * 2) ^ ((c & 7) << 4);
    const unsigned short* bfr_base = cbn_sT + (size_t)(n0 + wn * 32 + c) * 8192 + g * 8;
    const int rd_row = wm * 32 + c;

    // prologue: gen tile 0 synchronously into Alds0
    {
        short8 b0 = ld8(gb), b1 = ld8(gb + 32);
        f32x4 sj4 = *reinterpret_cast<const f32x4*>(sb);
        f32x4 gf = {0.f, 0.f, 0.f, 0.f};
        gf = MFMA16(b0, ga0, gf);
        gf = MFMA16(b1, ga1, gf);
        unsigned short u[4];
        #pragma unroll
        for (int r = 0; r < 4; ++r) {
            float t = fmaf(2.f, gf[r], -(si + sj4[r]));
            float x = fmaxf(fmaf(fabsf(t), -0.015625f, 1.f), 0.f);
            u[r] = f2bf(pow14(x));
        }
        *reinterpret_cast<uint2*>(&Alds0[wr_bo]) =
            make_uint2((unsigned)u[0] | ((unsigned)u[1] << 16),
                       (unsigned)u[2] | ((unsigned)u[3] << 16));
    }
    // issue gen loads for tile 1 (consumed at iter 0's gen-compute)
    short8 bA0 = ld8(gb + 64 * 64), bA1 = ld8(gb + 64 * 64 + 32);
    f32x4 sjA = *reinterpret_cast<const f32x4*>(sb + 64);
    short8 bB0, bB1; f32x4 sjB;
    BARRIER_LGKM();

#define SPEC_ITER(T, LR, LW, bc0, bc1, sjc, bn0, bn1, sjn) do {                    \
    const int j0_ = (T) << 6;                                                      \
    const int jn_ = ((T) + 2 < 128) ? (j0_ + 128) : 0;                             \
    bn0 = ld8(gb + jn_ * 64);                                                      \
    bn1 = ld8(gb + jn_ * 64 + 32);                                                 \
    sjn = *reinterpret_cast<const f32x4*>(sb + jn_);                               \
    short8 bfr_[2][2];                                                             \
    _Pragma("unroll")                                                              \
    for (int kk = 0; kk < 2; ++kk)                                                 \
        _Pragma("unroll")                                                          \
        for (int nn = 0; nn < 2; ++nn)                                             \
            bfr_[kk][nn] = ld8(bfr_base + (size_t)nn * 16 * 8192 + j0_ + kk * 32); \
    short8 af_[2][2];                                                              \
    _Pragma("unroll")                                                              \
    for (int mi = 0; mi < 2; ++mi)                                                 \
        _Pragma("unroll")                                                          \
        for (int kk = 0; kk < 2; ++kk) {                                           \
            int bo_ = ((rd_row + mi * 16) * 128 + kk * 64 + g * 16) ^ ((c & 7) << 4); \
            af_[mi][kk] = *reinterpret_cast<const short8*>(&(LR)[bo_]);            \
        }                                                                          \
    if ((T) < 127) {  /* gen tile T+1 from regs loaded last iter */                \
        f32x4 gf_ = {0.f, 0.f, 0.f, 0.f};                                          \
        gf_ = MFMA16(bc0, ga0, gf_);                                               \
        gf_ = MFMA16(bc1, ga1, gf_);                                               \
        unsigned short u_[4];                                                      \
        _Pragma("unroll")                                                          \
        for (int r = 0; r < 4; ++r) {                                              \
            float t_ = fmaf(2.f, gf_[r], -(si + (sjc)[r]));                        \
            float x_ = fmaxf(fmaf(fabsf(t_), -0.015625f, 1.f), 0.f);               \
            u_[r] = f2bf(pow14(x_));                                               \
        }                                                                          \
        *reinterpret_cast<uint2*>(&(LW)[wr_bo]) =                                  \
            make_uint2((unsigned)u_[0] | ((unsigned)u_[1] << 16),                  \
                       (unsigned)u_[2] | ((unsigned)u_[3] << 16));                 \
    }                                                                              \
    __builtin_amdgcn_s_setprio(1);                                                 \
    _Pragma("unroll")                                                              \
    for (int kk = 0; kk < 2; ++kk)                                                 \
        _Pragma("unroll")                                                          \
        for (int nn = 0; nn < 2; ++nn) {                                           \
            acc[0][nn] = MFMA16(af_[0][kk], bfr_[kk][nn], acc[0][nn]);             \
            acc[1][nn] = MFMA16(af_[1][kk], bfr_[kk][nn], acc[1][nn]);             \
        }                                                                          \
    __builtin_amdgcn_s_setprio(0);                                                 \
    BARRIER_LGKM();                                                                \
} while (0)

    for (int t2 = 0; t2 < 64; ++t2) {
        SPEC_ITER(2 * t2,     Alds0, Alds1, bA0, bA1, sjA, bB0, bB1, sjB);
        SPEC_ITER(2 * t2 + 1, Alds1, Alds0, bB0, bB1, sjB, bA0, bA1, sjA);
    }
#undef SPEC_ITER

    // epilogue: scale by dinv_i, store bf16 h
    #pragma unroll
    for (int mi = 0; mi < 2; ++mi) {
        f32x4 d4 = *reinterpret_cast<const f32x4*>(d + i0 + wm * 32 + mi * 16 + g * 4);
        #pragma unroll
        for (int r = 0; r < 4; ++r) {
            int row = i0 + wm * 32 + mi * 16 + g * 4 + r;
            float dinv = rsqrtf(d4[r]);
            #pragma unroll
            for (int nn = 0; nn < 2; ++nn)
                h[(size_t)row * 512 + n0 + wn * 32 + nn * 16 + c] = f2bf(acc[mi][nn][r] * dinv);
        }
    }
}

// ---- K4: out = sigmoid(h @ W + b), fp32 out ----------------------------------
__global__ __launch_bounds__(512) void k_out(const unsigned short* __restrict__ h,
                                             const unsigned short* __restrict__ Wt,
                                             const float* __restrict__ b,
                                             float* __restrict__ out) {
    int bx = blockIdx.x;
    int i0 = (bx & 255) * 32, n0 = (bx >> 8) * 256;
    int tid = threadIdx.x;
    int w = tid >> 6, l = tid & 63, g = l >> 4, c = l & 15;
    int wm = w >> 2, wn = w & 3;   // rows wm*16, cols wn*64

    float bb[4];
    #pragma unroll
    for (int nn = 0; nn < 4; ++nn) bb[nn] = b[n0 + wn * 64 + nn * 16 + c];

    f32x4 acc[4] = {};
    for (int k0 = 0; k0 < 512; k0 += 64) {
        short8 af[2];
        #pragma unroll
        for (int kk = 0; kk < 2; ++kk)
            af[kk] = ld8(h + (size_t)(i0 + wm * 16 + c) * 512 + k0 + kk * 32 + g * 8);
        #pragma unroll
        for (int kk = 0; kk < 2; ++kk)
            #pragma unroll
            for (int nn = 0; nn < 4; ++nn) {
                short8 bf = ld8(Wt + (size_t)(n0 + wn * 64 + nn * 16 + c) * 512 + k0 + kk * 32 + g * 8);
                acc[nn] = MFMA16(af[kk], bf, acc[nn]);
            }
    }
    #pragma unroll
    for (int r = 0; r < 4; ++r) {
        int row = i0 + wm * 16 + g * 4 + r;
        #pragma unroll
        for (int nn = 0; nn < 4; ++nn) {
            float z = acc[nn][r] + bb[nn];
            out[(size_t)row * 512 + n0 + wn * 64 + nn * 16 + c] = 1.f / (1.f + exp2f(-1.44269504f * z));
        }
    }
}

extern "C" void kernel_launch(void* const* d_in, const int* in_sizes, int n_in,
                              void* d_out, int out_size, void* d_ws, size_t ws_size,
                              hipStream_t stream) {
    const float* bbn = (const float*)d_in[0];   // [8192, 64]
    const float* cbn = (const float*)d_in[1];   // [8192, 512]
    const float* W   = (const float*)d_in[2];   // [512, 512]
    const float* b   = (const float*)d_in[3];   // [512]
    float* out = (float*)d_out;                 // [8192, 512] fp32

    char* ws = (char*)d_ws;
    unsigned short* bbn_h  = (unsigned short*)(ws);                    // 1 MB
    float*          s      = (float*)(ws + (1u << 20));                // 32 KB
    float*          dd     = (float*)(ws + (1u << 20) + (1u << 15));   // 32 KB
    unsigned short* Wt     = (unsigned short*)(ws + (1u << 20) + (2u << 15));           // 512 KB
    unsigned short* cbn_sT = (unsigned short*)(ws + (1u << 20) + (2u << 15) + (1u << 19));        // 8 MB
    unsigned short* hbuf   = (unsigned short*)(ws + (1u << 20) + (2u << 15) + (1u << 19) + (1u << 23)); // 8 MB

    k_prep_bbn<<<2048, 256, 0, stream>>>(bbn, bbn_h, s);
    k_transpose_scale<<<64, 256, 0, stream>>>(W, Wt, nullptr, 512, 512);
    k_degree<<<512, 512, 0, stream>>>(bbn_h, s, dd);
    k_transpose_scale<<<1024, 256, 0, stream>>>(cbn, cbn_sT, dd, 8192, 512);
    k_spectral<<<256, 1024, 0, stream>>>(bbn_h, s, dd, cbn_sT, hbuf);
    k_out<<<512, 512, 0, stream>>>(hbuf, Wt, b, out);
}

// Round 9
// 271.388 us; speedup vs baseline: 2.3166x; 1.8616x over previous
//
#include <hip/hip_runtime.h>
#include <hip/hip_bf16.h>

typedef __attribute__((ext_vector_type(8))) short short8;
typedef __attribute__((ext_vector_type(4))) float f32x4;

#define MFMA16(a, b, c) __builtin_amdgcn_mfma_f32_16x16x32_bf16((a), (b), (c), 0, 0, 0)

// loop barrier: drain LDS ops + all VMEM except the newest (sj prefetch).
#define BARRIER_V1() asm volatile("s_waitcnt vmcnt(1) lgkmcnt(0)\ns_barrier" ::: "memory")
#define BARRIER_V0() asm volatile("s_waitcnt vmcnt(0) lgkmcnt(0)\ns_barrier" ::: "memory")
#define BARRIER_LG() asm volatile("s_waitcnt lgkmcnt(0)\ns_barrier" ::: "memory")

__device__ __forceinline__ unsigned short f2bf(float x) {
    union { float f; unsigned int u; } v; v.f = x;
    unsigned int u = v.u;
    return (unsigned short)((u + 0x7FFFu + ((u >> 16) & 1u)) >> 16);
}

// r4/r8-proven numerics: libm exp2f/log2f
__device__ __forceinline__ float pow14(float x) {
    return exp2f(1.4f * log2f(x));
}

__device__ __forceinline__ short8 ld8(const unsigned short* p) {
    return *reinterpret_cast<const short8*>(p);
}

// async global->LDS, 16B/lane; dest = wave-uniform base + lane*16 (linear)
__device__ __forceinline__ void gld16(const unsigned short* src, unsigned char* dst) {
    __builtin_amdgcn_global_load_lds(
        (const __attribute__((address_space(1))) void*)src,
        (__attribute__((address_space(3))) void*)dst, 16, 0, 0);
}

// ---- K0: bbn fp32 -> bf16 (plain + row-swizzled copy), row sums s[i] ---------
__global__ void k_prep_bbn(const float* __restrict__ bbn, unsigned short* __restrict__ bbn_h,
                           unsigned short* __restrict__ bbn_swz, float* __restrict__ s) {
    int row = blockIdx.x * 4 + (threadIdx.x >> 6);
    int lane = threadIdx.x & 63;
    float x = bbn[row * 64 + lane];
    unsigned short h = f2bf(x);
    bbn_h[row * 64 + lane] = h;
    // swizzled copy: swz[row][p] = h[row][p ^ ((row&7)<<3)] (elems; <<4 in bytes)
    bbn_swz[row * 64 + (lane ^ ((row & 7) << 3))] = h;
    float v = x;
    #pragma unroll
    for (int m = 1; m < 64; m <<= 1) v += __shfl_xor(v, m);
    if (lane == 0) s[row] = v;
}

// ---- K0b/K2: transpose (+optional rsqrt(d) row scale, optional swizzle) ------
__global__ void k_transpose_scale(const float* __restrict__ in, unsigned short* __restrict__ out,
                                  const float* __restrict__ dvec, int K, int N, int swz) {
    __shared__ float tile[64][65];
    int tiles_k = K >> 6;
    int tk = blockIdx.x % tiles_k, tn = blockIdx.x / tiles_k;
    int k0 = tk * 64, n0 = tn * 64;
    int c = threadIdx.x & 63, rq = threadIdx.x >> 6;
    #pragma unroll
    for (int i = 0; i < 16; ++i) {
        int r = rq + 4 * i;
        float sc = dvec ? rsqrtf(dvec[k0 + r]) : 1.0f;
        tile[r][c] = in[(size_t)(k0 + r) * N + n0 + c] * sc;
    }
    __syncthreads();
    #pragma unroll
    for (int i = 0; i < 16; ++i) {
        int r = rq + 4 * i;
        int cc = swz ? (c ^ ((r & 7) << 3)) : c;
        out[(size_t)(n0 + r) * K + k0 + cc] = f2bf(tile[c][r]);
    }
}

// ---- K1: degree d[i] = sum_j (1 - |2*G_ij - s_i - s_j|/64)^1.4 ---------------
__global__ __launch_bounds__(512) void k_degree(const unsigned short* __restrict__ bbn_h,
                                                const float* __restrict__ s,
                                                float* __restrict__ d) {
    int i0 = blockIdx.x * 16;
    int tid = threadIdx.x;
    int w = tid >> 6, l = tid & 63, g = l >> 4, c = l & 15;

    const unsigned short* ap = bbn_h + (i0 + c) * 64;
    short8 a0 = ld8(ap);
    short8 a1 = ld8(ap + 32);
    f32x4 si4 = *reinterpret_cast<const f32x4*>(s + i0 + g * 4);

    float acc[4] = {0.f, 0.f, 0.f, 0.f};
    #pragma unroll 4
    for (int j0 = w * 16; j0 < 8192; j0 += 128) {
        int jrow = j0 + c;
        const unsigned short* bp = bbn_h + jrow * 64;
        short8 b0 = ld8(bp);
        short8 b1 = ld8(bp + 32);
        float sj = s[jrow];
        f32x4 gf = {0.f, 0.f, 0.f, 0.f};
        gf = MFMA16(a0, b0, gf);
        gf = MFMA16(a1, b1, gf);
        #pragma unroll
        for (int r = 0; r < 4; ++r) {
            float t = fmaf(2.f, gf[r], -(si4[r] + sj));
            float x = fmaxf(fmaf(fabsf(t), -0.015625f, 1.f), 0.f);
            acc[r] += pow14(x);
        }
    }

    __shared__ float part[8][16];
    #pragma unroll
    for (int r = 0; r < 4; ++r) {
        float v = acc[r];
        v += __shfl_xor(v, 1); v += __shfl_xor(v, 2);
        v += __shfl_xor(v, 4); v += __shfl_xor(v, 8);
        if (c == 0) part[w][g * 4 + r] = v;
    }
    __syncthreads();
    if (tid < 16) {
        float v = 0.f;
        #pragma unroll
        for (int ww = 0; ww < 8; ++ww) v += part[ww][tid];
        d[i0 + tid] = v;
    }
}

// ---- K3: fused h = D^-1/2 A D^-1/2 cbn ---------------------------------------
// BM=64, BN=256, BK=64; 1024 threads (16 waves). Main: 2x8 waves, 32x32/wave.
// ALL bulk global traffic now goes through global_load_lds (coalesced 128B
// transactions) instead of 16-row-strided ld8 (16 transactions/inst) — the
// per-CU transaction wall that pinned r2-r8 at ~7500cy/iter.
// Pipeline: stage B(t+1) + Aj(t+2) at iter t; barrier drains them (vmcnt(1)
// keeps only the sj prefetch in flight). Gen tile t+1 from Ajlds; A,B,Aj all
// double-buffered; one barrier/iter.
__global__ __launch_bounds__(1024, 4) void k_spectral(const unsigned short* __restrict__ bbn_h,
                                                      const unsigned short* __restrict__ bbn_swz,
                                                      const float* __restrict__ s,
                                                      const float* __restrict__ d,
                                                      const unsigned short* __restrict__ cbn_sT,
                                                      unsigned short* __restrict__ h) {
    int bx = blockIdx.x;
    int xcd = bx & 7, hi = bx >> 3;
    int i0 = (hi * 4 + (xcd & 3)) * 64;
    int n0 = (xcd >> 2) * 256;

    int tid = threadIdx.x;
    int w = tid >> 6, l = tid & 63, g = l >> 4, c = l & 15;
    int wm = w >> 3, wn = w & 7;      // main wave tile: rows wm*32, cols wn*32
    int gi = w & 3, gj = w >> 2;      // gen subtile: i-rows gi*16, j-rows gj*16
    int lrow = l >> 3, lseg = l & 7;  // staging lane roles

    const unsigned short* ap = bbn_h + (i0 + gi * 16 + c) * 64;
    short8 ga0 = ld8(ap), ga1 = ld8(ap + 32);
    float si = s[i0 + gi * 16 + c];

    __shared__ unsigned char Almain[2][8192];   // generated A tile, XOR-swz
    __shared__ unsigned char Blds[2][32768];    // B tile [256 n][128B j], XOR-swz
    __shared__ unsigned char Ajlds[2][8192];    // bbn j-rows [64][128B], XOR-swz

    f32x4 acc[2][2] = {};

    // staging sources (pre-swizzled in memory -> linear glds reads)
    const unsigned short* bsrc0 = cbn_sT + (size_t)(n0 + w * 16 + lrow) * 8192 + lseg * 8;
    const unsigned short* bsrc1 = bsrc0 + (size_t)8 * 8192;
    const unsigned short* ajsrc = bbn_swz + (w * 8 + lrow) * 64 + lseg * 8;  // + tile*4096

    const int sw = (c & 7) << 4;
    const int gj_bo0 = (gj * 16 + c) * 128 + ((g * 16) ^ sw);
    const int gj_bo1 = (gj * 16 + c) * 128 + ((64 + g * 16) ^ sw);
    const float* sb = s + gj * 16 + g * 4;
    const int wr_bo = ((gi * 16 + c) * 128 + (gj * 16 + g * 4) * 2) ^ sw;

    // prologue: stage B(0)->Blds[0], Aj(0)->Ajlds[0], Aj(1)->Ajlds[1]
    gld16(bsrc0, &Blds[0][(w * 16) * 128]);
    gld16(bsrc1, &Blds[0][(w * 16 + 8) * 128]);
    if (w < 8) {
        gld16(ajsrc,        &Ajlds[0][(w * 8) * 128]);
        gld16(ajsrc + 4096, &Ajlds[1][(w * 8) * 128]);
    }
    BARRIER_V0();
    // gen tile 0 -> Almain[0]
    {
        short8 b0 = *reinterpret_cast<const short8*>(&Ajlds[0][gj_bo0]);
        short8 b1 = *reinterpret_cast<const short8*>(&Ajlds[0][gj_bo1]);
        f32x4 sj4 = *reinterpret_cast<const f32x4*>(sb);
        f32x4 gf = {0.f, 0.f, 0.f, 0.f};
        gf = MFMA16(b0, ga0, gf);
        gf = MFMA16(b1, ga1, gf);
        unsigned short u[4];
        #pragma unroll
        for (int r = 0; r < 4; ++r) {
            float t = fmaf(2.f, gf[r], -(si + sj4[r]));
            float x = fmaxf(fmaf(fabsf(t), -0.015625f, 1.f), 0.f);
            u[r] = f2bf(pow14(x));
        }
        *reinterpret_cast<uint2*>(&Almain[0][wr_bo]) =
            make_uint2((unsigned)u[0] | ((unsigned)u[1] << 16),
                       (unsigned)u[2] | ((unsigned)u[3] << 16));
    }
    f32x4 sjA = *reinterpret_cast<const f32x4*>(sb + 64);  // sj(tile 1)
    f32x4 sjB;
    BARRIER_LG();

#define SPEC_ITER(T, CUR, NXT, sjc, sjn) do {                                       \
    const int jB_ = (((T) + 1 < 128) ? (T) + 1 : 127) << 6;   /* elems */           \
    const int jA_ = (((T) + 2 < 128) ? (T) + 2 : 127);        /* tile idx */        \
    gld16(bsrc0 + jB_, &Blds[NXT][(w * 16) * 128]);                                 \
    gld16(bsrc1 + jB_, &Blds[NXT][(w * 16 + 8) * 128]);                             \
    __builtin_amdgcn_sched_barrier(0);                                              \
    if (w < 8) gld16(ajsrc + jA_ * 4096, &Ajlds[CUR][(w * 8) * 128]);               \
    __builtin_amdgcn_sched_barrier(0);                                              \
    sjn = *reinterpret_cast<const f32x4*>(sb + jA_ * 64);                           \
    short8 af_[2][2], bf_[2][2];                                                    \
    _Pragma("unroll")                                                               \
    for (int mi = 0; mi < 2; ++mi)                                                  \
        _Pragma("unroll")                                                           \
        for (int kk = 0; kk < 2; ++kk)                                              \
            af_[mi][kk] = *reinterpret_cast<const short8*>(                         \
                &Almain[CUR][(wm * 32 + mi * 16 + c) * 128 + ((kk * 64 + g * 16) ^ sw)]); \
    _Pragma("unroll")                                                               \
    for (int kk = 0; kk < 2; ++kk)                                                  \
        _Pragma("unroll")                                                           \
        for (int nn = 0; nn < 2; ++nn)                                              \
            bf_[kk][nn] = *reinterpret_cast<const short8*>(                         \
                &Blds[CUR][(wn * 32 + nn * 16 + c) * 128 + ((kk * 64 + g * 16) ^ sw)]); \
    {   /* gen tile T+1 from Ajlds[NXT] */                                          \
        short8 gb0 = *reinterpret_cast<const short8*>(&Ajlds[NXT][gj_bo0]);         \
        short8 gb1 = *reinterpret_cast<const short8*>(&Ajlds[NXT][gj_bo1]);         \
        f32x4 gf_ = {0.f, 0.f, 0.f, 0.f};                                           \
        gf_ = MFMA16(gb0, ga0, gf_);                                                \
        gf_ = MFMA16(gb1, ga1, gf_);                                                \
        unsigned short u_[4];                                                       \
        _Pragma("unroll")                                                           \
        for (int r = 0; r < 4; ++r) {                                               \
            float t_ = fmaf(2.f, gf_[r], -(si + (sjc)[r]));                         \
            float x_ = fmaxf(fmaf(fabsf(t_), -0.015625f, 1.f), 0.f);                \
            u_[r] = f2bf(pow14(x_));                                                \
        }                                                                           \
        *reinterpret_cast<uint2*>(&Almain[NXT][wr_bo]) =                            \
            make_uint2((unsigned)u_[0] | ((unsigned)u_[1] << 16),                   \
                       (unsigned)u_[2] | ((unsigned)u_[3] << 16));                  \
    }                                                                               \
    __builtin_amdgcn_s_setprio(1);                                                  \
    _Pragma("unroll")                                                               \
    for (int kk = 0; kk < 2; ++kk)                                                  \
        _Pragma("unroll")                                                           \
        for (int nn = 0; nn < 2; ++nn) {                                            \
            acc[0][nn] = MFMA16(af_[0][kk], bf_[kk][nn], acc[0][nn]);               \
            acc[1][nn] = MFMA16(af_[1][kk], bf_[kk][nn], acc[1][nn]);               \
        }                                                                           \
    __builtin_amdgcn_s_setprio(0);                                                  \
    BARRIER_V1();                                                                   \
} while (0)

    for (int t2 = 0; t2 < 64; ++t2) {
        SPEC_ITER(2 * t2,     0, 1, sjA, sjB);
        SPEC_ITER(2 * t2 + 1, 1, 0, sjB, sjA);
    }
#undef SPEC_ITER

    // epilogue: scale by dinv_i, store bf16 h
    #pragma unroll
    for (int mi = 0; mi < 2; ++mi) {
        f32x4 d4 = *reinterpret_cast<const f32x4*>(d + i0 + wm * 32 + mi * 16 + g * 4);
        #pragma unroll
        for (int r = 0; r < 4; ++r) {
            int row = i0 + wm * 32 + mi * 16 + g * 4 + r;
            float dinv = rsqrtf(d4[r]);
            #pragma unroll
            for (int nn = 0; nn < 2; ++nn)
                h[(size_t)row * 512 + n0 + wn * 32 + nn * 16 + c] = f2bf(acc[mi][nn][r] * dinv);
        }
    }
}

// ---- K4: out = sigmoid(h @ W + b), fp32 out ----------------------------------
__global__ __launch_bounds__(512) void k_out(const unsigned short* __restrict__ h,
                                             const unsigned short* __restrict__ Wt,
                                             const float* __restrict__ b,
                                             float* __restrict__ out) {
    int bx = blockIdx.x;
    int i0 = (bx & 255) * 32, n0 = (bx >> 8) * 256;
    int tid = threadIdx.x;
    int w = tid >> 6, l = tid & 63, g = l >> 4, c = l & 15;
    int wm = w >> 2, wn = w & 3;   // rows wm*16, cols wn*64

    float bb[4];
    #pragma unroll
    for (int nn = 0; nn < 4; ++nn) bb[nn] = b[n0 + wn * 64 + nn * 16 + c];

    f32x4 acc[4] = {};
    for (int k0 = 0; k0 < 512; k0 += 64) {
        short8 af[2];
        #pragma unroll
        for (int kk = 0; kk < 2; ++kk)
            af[kk] = ld8(h + (size_t)(i0 + wm * 16 + c) * 512 + k0 + kk * 32 + g * 8);
        #pragma unroll
        for (int kk = 0; kk < 2; ++kk)
            #pragma unroll
            for (int nn = 0; nn < 4; ++nn) {
                short8 bf = ld8(Wt + (size_t)(n0 + wn * 64 + nn * 16 + c) * 512 + k0 + kk * 32 + g * 8);
                acc[nn] = MFMA16(af[kk], bf, acc[nn]);
            }
    }
    #pragma unroll
    for (int r = 0; r < 4; ++r) {
        int row = i0 + wm * 16 + g * 4 + r;
        #pragma unroll
        for (int nn = 0; nn < 4; ++nn) {
            float z = acc[nn][r] + bb[nn];
            out[(size_t)row * 512 + n0 + wn * 64 + nn * 16 + c] = 1.f / (1.f + exp2f(-1.44269504f * z));
        }
    }
}

extern "C" void kernel_launch(void* const* d_in, const int* in_sizes, int n_in,
                              void* d_out, int out_size, void* d_ws, size_t ws_size,
                              hipStream_t stream) {
    const float* bbn = (const float*)d_in[0];   // [8192, 64]
    const float* cbn = (const float*)d_in[1];   // [8192, 512]
    const float* W   = (const float*)d_in[2];   // [512, 512]
    const float* b   = (const float*)d_in[3];   // [512]
    float* out = (float*)d_out;                 // [8192, 512] fp32

    char* ws = (char*)d_ws;
    unsigned short* bbn_h   = (unsigned short*)(ws);                    // 1 MB @ 0
    unsigned short* bbn_swz = (unsigned short*)(ws + (1u << 20));       // 1 MB @ 1M
    float*          s       = (float*)(ws + (2u << 20));                // 32 KB
    float*          dd      = (float*)(ws + (2u << 20) + (1u << 15));   // 32 KB
    unsigned short* Wt      = (unsigned short*)(ws + (2u << 20) + (2u << 15));  // 512 KB
    unsigned short* cbn_sT  = (unsigned short*)(ws + (3u << 20));       // 8 MB (swizzled, dinv_j-scaled)
    unsigned short* hbuf    = (unsigned short*)(ws + (11u << 20));      // 8 MB

    k_prep_bbn<<<2048, 256, 0, stream>>>(bbn, bbn_h, bbn_swz, s);
    k_transpose_scale<<<64, 256, 0, stream>>>(W, Wt, nullptr, 512, 512, 0);
    k_degree<<<512, 512, 0, stream>>>(bbn_h, s, dd);
    k_transpose_scale<<<1024, 256, 0, stream>>>(cbn, cbn_sT, dd, 8192, 512, 1);
    k_spectral<<<256, 1024, 0, stream>>>(bbn_h, bbn_swz, s, dd, cbn_sT, hbuf);
    k_out<<<512, 512, 0, stream>>>(hbuf, Wt, b, out);
}

// Round 10
// 266.897 us; speedup vs baseline: 2.3556x; 1.0168x over previous
//
#include <hip/hip_runtime.h>
#include <hip/hip_bf16.h>

typedef __attribute__((ext_vector_type(8))) short short8;
typedef __attribute__((ext_vector_type(4))) float f32x4;

#define MFMA16(a, b, c) __builtin_amdgcn_mfma_f32_16x16x32_bf16((a), (b), (c), 0, 0, 0)

#define BARRIER_V0() asm volatile("s_waitcnt vmcnt(0) lgkmcnt(0)\ns_barrier" ::: "memory")
#define BARRIER_LG() asm volatile("s_waitcnt lgkmcnt(0)\ns_barrier" ::: "memory")

__device__ __forceinline__ unsigned short f2bf(float x) {
    union { float f; unsigned int u; } v; v.f = x;
    unsigned int u = v.u;
    return (unsigned short)((u + 0x7FFFu + ((u >> 16) & 1u)) >> 16);
}

// r4/r8-proven numerics: libm exp2f/log2f
__device__ __forceinline__ float pow14(float x) {
    return exp2f(1.4f * log2f(x));
}

__device__ __forceinline__ short8 ld8(const unsigned short* p) {
    return *reinterpret_cast<const short8*>(p);
}

__device__ __forceinline__ void gld16(const unsigned short* src, unsigned char* dst) {
    __builtin_amdgcn_global_load_lds(
        (const __attribute__((address_space(1))) void*)src,
        (__attribute__((address_space(3))) void*)dst, 16, 0, 0);
}

// ---- K0: bbn fp32 -> bf16 (plain + row-swizzled copy), row sums s[i] ---------
__global__ void k_prep_bbn(const float* __restrict__ bbn, unsigned short* __restrict__ bbn_h,
                           unsigned short* __restrict__ bbn_swz, float* __restrict__ s) {
    int row = blockIdx.x * 4 + (threadIdx.x >> 6);
    int lane = threadIdx.x & 63;
    float x = bbn[row * 64 + lane];
    unsigned short h = f2bf(x);
    bbn_h[row * 64 + lane] = h;
    bbn_swz[row * 64 + (lane ^ ((row & 7) << 3))] = h;
    float v = x;
    #pragma unroll
    for (int m = 1; m < 64; m <<= 1) v += __shfl_xor(v, m);
    if (lane == 0) s[row] = v;
}

__global__ void k_zero_d(float* __restrict__ dd) {
    dd[blockIdx.x * 1024 + threadIdx.x] = 0.f;
}

// ---- K0b/K2: transpose (+optional rsqrt(d) row scale, optional swizzle) ------
__global__ void k_transpose_scale(const float* __restrict__ in, unsigned short* __restrict__ out,
                                  const float* __restrict__ dvec, int K, int N, int swz) {
    __shared__ float tile[64][65];
    int tiles_k = K >> 6;
    int tk = blockIdx.x % tiles_k, tn = blockIdx.x / tiles_k;
    int k0 = tk * 64, n0 = tn * 64;
    int c = threadIdx.x & 63, rq = threadIdx.x >> 6;
    #pragma unroll
    for (int i = 0; i < 16; ++i) {
        int r = rq + 4 * i;
        float sc = dvec ? rsqrtf(dvec[k0 + r]) : 1.0f;
        tile[r][c] = in[(size_t)(k0 + r) * N + n0 + c] * sc;
    }
    __syncthreads();
    #pragma unroll
    for (int i = 0; i < 16; ++i) {
        int r = rq + 4 * i;
        int cc = swz ? (c ^ ((r & 7) << 3)) : c;
        out[(size_t)(n0 + r) * K + k0 + cc] = f2bf(tile[c][r]);
    }
}

// ---- K1: materialize A (swizzled bf16) + degree d[i] (fused) ------------------
// grid 256 = 128 i-tiles x 2 j-halves; 1024 threads, 16 waves (gi=w&3, gj=w>>2).
// Gen math identical to r9 (swapped MFMA, pow14, f2bf). A-tile bounced through
// LDS (already swizzled layout) then copied out coalesced. Degree via in-lane
// sum + shfl over g-lanes + one atomicAdd per (wave,c) at the end.
__global__ __launch_bounds__(1024, 2) void k_gen_adj(const unsigned short* __restrict__ bbn_h,
                                                     const unsigned short* __restrict__ bbn_swz,
                                                     const float* __restrict__ s,
                                                     unsigned short* __restrict__ A_swz,
                                                     float* __restrict__ dd) {
    int bx = blockIdx.x;
    int it = bx >> 1, jh = bx & 1;
    int i0 = it * 64, jbase = jh * 4096;

    int tid = threadIdx.x;
    int w = tid >> 6, l = tid & 63, g = l >> 4, c = l & 15;
    int gi = w & 3, gj = w >> 2;
    int lrow = l >> 3, lseg = l & 7;

    const unsigned short* ap = bbn_h + (i0 + gi * 16 + c) * 64;
    short8 ga0 = ld8(ap), ga1 = ld8(ap + 32);
    float si = s[i0 + gi * 16 + c];

    __shared__ unsigned char Ajlds[2][8192];
    __shared__ unsigned char Outlds[2][8192];

    const unsigned short* ajbase = bbn_swz + (jbase + w * 8 + lrow) * 64 + lseg * 8; // + t*4096
    const int sw = (c & 7) << 4;
    const int gj_bo0 = (gj * 16 + c) * 128 + ((g * 16) ^ sw);
    const int gj_bo1 = (gj * 16 + c) * 128 + ((64 + g * 16) ^ sw);
    const float* sb = s + jbase + gj * 16 + g * 4;   // + t*64
    const int wr_bo = ((gi * 16 + c) * 128 + (gj * 16 + g * 4) * 2) ^ sw;

    float racc = 0.f;

#define GEN_TILE(T, BUF) do {                                                      \
    short8 gb0 = *reinterpret_cast<const short8*>(&Ajlds[(T) & 1][gj_bo0]);        \
    short8 gb1 = *reinterpret_cast<const short8*>(&Ajlds[(T) & 1][gj_bo1]);        \
    f32x4 sj4 = *reinterpret_cast<const f32x4*>(sb + (T) * 64);                    \
    f32x4 gf = {0.f, 0.f, 0.f, 0.f};                                               \
    gf = MFMA16(gb0, ga0, gf);                                                     \
    gf = MFMA16(gb1, ga1, gf);                                                     \
    float u0, u1, u2, u3;                                                          \
    {                                                                              \
        float t0 = fmaf(2.f, gf[0], -(si + sj4[0]));                               \
        float t1 = fmaf(2.f, gf[1], -(si + sj4[1]));                               \
        float t2 = fmaf(2.f, gf[2], -(si + sj4[2]));                               \
        float t3 = fmaf(2.f, gf[3], -(si + sj4[3]));                               \
        u0 = pow14(fmaxf(fmaf(fabsf(t0), -0.015625f, 1.f), 0.f));                  \
        u1 = pow14(fmaxf(fmaf(fabsf(t1), -0.015625f, 1.f), 0.f));                  \
        u2 = pow14(fmaxf(fmaf(fabsf(t2), -0.015625f, 1.f), 0.f));                  \
        u3 = pow14(fmaxf(fmaf(fabsf(t3), -0.015625f, 1.f), 0.f));                  \
    }                                                                              \
    racc += (u0 + u1) + (u2 + u3);                                                 \
    unsigned short p0 = f2bf(u0), p1 = f2bf(u1), p2 = f2bf(u2), p3 = f2bf(u3);     \
    *reinterpret_cast<uint2*>(&Outlds[BUF][wr_bo]) =                               \
        make_uint2((unsigned)p0 | ((unsigned)p1 << 16),                            \
                   (unsigned)p2 | ((unsigned)p3 << 16));                           \
} while (0)

    // prologue: stage Aj(0), Aj(1); gen tile 0
    if (w < 8) {
        gld16(ajbase,        &Ajlds[0][(w * 8) * 128]);
        gld16(ajbase + 4096, &Ajlds[1][(w * 8) * 128]);
    }
    BARRIER_V0();
    GEN_TILE(0, 0);
    BARRIER_LG();

    for (int t = 1; t <= 64; ++t) {
        if (w < 8 && t <= 62) gld16(ajbase + (t + 1) * 4096, &Ajlds[(t + 1) & 1][(w * 8) * 128]);
        if (t <= 63) GEN_TILE(t, t & 1);
        // copy tile t-1 -> global (coalesced)
        {
            int row = tid >> 4, col8 = tid & 15;
            uint2 v = *reinterpret_cast<const uint2*>(&Outlds[(t - 1) & 1][tid * 8]);
            *reinterpret_cast<uint2*>(A_swz + (size_t)(i0 + row) * 8192 + jbase + (t - 1) * 64 + col8 * 4) = v;
        }
        BARRIER_V0();
    }
#undef GEN_TILE

    // degree: reduce over g-lanes (j-subrange within wave), atomic per (gj,gi,c)
    racc += __shfl_xor(racc, 16);
    racc += __shfl_xor(racc, 32);
    if (g == 0) atomicAdd(&dd[i0 + gi * 16 + c], racc);
}

// ---- K3: pure GEMM h = A_swz @ cbn_sT^T (dinv_j pre-folded), dinv_i epilogue --
// BM=64, BN=256, BK=64; 1024 threads, 16 waves (2x8), 32x32/wave.
// Stage A-tile (8KB) + B-tile (32KB) per iter via global_load_lds; 8 ds_read
// + 8 MFMA per wave per iter. Double-buffered, one vmcnt(0) barrier/iter.
__global__ __launch_bounds__(1024, 2) void k_spectral(const unsigned short* __restrict__ A_swz,
                                                      const float* __restrict__ d,
                                                      const unsigned short* __restrict__ cbn_sT,
                                                      unsigned short* __restrict__ h) {
    int bx = blockIdx.x;
    int xcd = bx & 7, hi = bx >> 3;
    int i0 = (hi * 4 + (xcd & 3)) * 64;
    int n0 = (xcd >> 2) * 256;

    int tid = threadIdx.x;
    int w = tid >> 6, l = tid & 63, g = l >> 4, c = l & 15;
    int wm = w >> 3, wn = w & 7;
    int lrow = l >> 3, lseg = l & 7;

    __shared__ unsigned char Alds[2][8192];
    __shared__ unsigned char Blds[2][32768];

    f32x4 acc[2][2] = {};

    const unsigned short* bsrc0 = cbn_sT + (size_t)(n0 + w * 16 + lrow) * 8192 + lseg * 8;
    const unsigned short* bsrc1 = bsrc0 + (size_t)8 * 8192;
    const unsigned short* asrc = A_swz + (size_t)(i0 + w * 8 + lrow) * 8192 + lseg * 8;

    const int sw = (c & 7) << 4;

    // prologue: stage tile 0
    gld16(bsrc0, &Blds[0][(w * 16) * 128]);
    gld16(bsrc1, &Blds[0][(w * 16 + 8) * 128]);
    if (w < 8) gld16(asrc, &Alds[0][(w * 8) * 128]);
    BARRIER_V0();

    for (int t = 0; t < 128; ++t) {
        int cur = t & 1, nxt = cur ^ 1;
        int jn = ((t + 1 < 128) ? t + 1 : 127) << 6;
        gld16(bsrc0 + jn, &Blds[nxt][(w * 16) * 128]);
        gld16(bsrc1 + jn, &Blds[nxt][(w * 16 + 8) * 128]);
        if (w < 8) gld16(asrc + jn, &Alds[nxt][(w * 8) * 128]);

        short8 af[2][2], bf[2][2];
        #pragma unroll
        for (int mi = 0; mi < 2; ++mi)
            #pragma unroll
            for (int kk = 0; kk < 2; ++kk)
                af[mi][kk] = *reinterpret_cast<const short8*>(
                    &Alds[cur][(wm * 32 + mi * 16 + c) * 128 + ((kk * 64 + g * 16) ^ sw)]);
        #pragma unroll
        for (int kk = 0; kk < 2; ++kk)
            #pragma unroll
            for (int nn = 0; nn < 2; ++nn)
                bf[kk][nn] = *reinterpret_cast<const short8*>(
                    &Blds[cur][(wn * 32 + nn * 16 + c) * 128 + ((kk * 64 + g * 16) ^ sw)]);

        __builtin_amdgcn_s_setprio(1);
        #pragma unroll
        for (int kk = 0; kk < 2; ++kk)
            #pragma unroll
            for (int nn = 0; nn < 2; ++nn) {
                acc[0][nn] = MFMA16(af[0][kk], bf[kk][nn], acc[0][nn]);
                acc[1][nn] = MFMA16(af[1][kk], bf[kk][nn], acc[1][nn]);
            }
        __builtin_amdgcn_s_setprio(0);
        BARRIER_V0();
    }

    // epilogue: scale by dinv_i, store bf16 h
    #pragma unroll
    for (int mi = 0; mi < 2; ++mi) {
        f32x4 d4 = *reinterpret_cast<const f32x4*>(d + i0 + wm * 32 + mi * 16 + g * 4);
        #pragma unroll
        for (int r = 0; r < 4; ++r) {
            int row = i0 + wm * 32 + mi * 16 + g * 4 + r;
            float dinv = rsqrtf(d4[r]);
            #pragma unroll
            for (int nn = 0; nn < 2; ++nn)
                h[(size_t)row * 512 + n0 + wn * 32 + nn * 16 + c] = f2bf(acc[mi][nn][r] * dinv);
        }
    }
}

// ---- K4: out = sigmoid(h @ W + b), fp32 out ----------------------------------
__global__ __launch_bounds__(512) void k_out(const unsigned short* __restrict__ h,
                                             const unsigned short* __restrict__ Wt,
                                             const float* __restrict__ b,
                                             float* __restrict__ out) {
    int bx = blockIdx.x;
    int i0 = (bx & 255) * 32, n0 = (bx >> 8) * 256;
    int tid = threadIdx.x;
    int w = tid >> 6, l = tid & 63, g = l >> 4, c = l & 15;
    int wm = w >> 2, wn = w & 3;

    float bb[4];
    #pragma unroll
    for (int nn = 0; nn < 4; ++nn) bb[nn] = b[n0 + wn * 64 + nn * 16 + c];

    f32x4 acc[4] = {};
    for (int k0 = 0; k0 < 512; k0 += 64) {
        short8 af[2];
        #pragma unroll
        for (int kk = 0; kk < 2; ++kk)
            af[kk] = ld8(h + (size_t)(i0 + wm * 16 + c) * 512 + k0 + kk * 32 + g * 8);
        #pragma unroll
        for (int kk = 0; kk < 2; ++kk)
            #pragma unroll
            for (int nn = 0; nn < 4; ++nn) {
                short8 bf = ld8(Wt + (size_t)(n0 + wn * 64 + nn * 16 + c) * 512 + k0 + kk * 32 + g * 8);
                acc[nn] = MFMA16(af[kk], bf, acc[nn]);
            }
    }
    #pragma unroll
    for (int r = 0; r < 4; ++r) {
        int row = i0 + wm * 16 + g * 4 + r;
        #pragma unroll
        for (int nn = 0; nn < 4; ++nn) {
            float z = acc[nn][r] + bb[nn];
            out[(size_t)row * 512 + n0 + wn * 64 + nn * 16 + c] = 1.f / (1.f + exp2f(-1.44269504f * z));
        }
    }
}

extern "C" void kernel_launch(void* const* d_in, const int* in_sizes, int n_in,
                              void* d_out, int out_size, void* d_ws, size_t ws_size,
                              hipStream_t stream) {
    const float* bbn = (const float*)d_in[0];   // [8192, 64]
    const float* cbn = (const float*)d_in[1];   // [8192, 512]
    const float* W   = (const float*)d_in[2];   // [512, 512]
    const float* b   = (const float*)d_in[3];   // [512]
    float* out = (float*)d_out;                 // [8192, 512] fp32

    char* ws = (char*)d_ws;
    unsigned short* bbn_h   = (unsigned short*)(ws);                    // 1 MB @ 0
    unsigned short* bbn_swz = (unsigned short*)(ws + (1u << 20));       // 1 MB @ 1M
    float*          s       = (float*)(ws + (2u << 20));                // 32 KB
    float*          dd      = (float*)(ws + (2u << 20) + (1u << 15));   // 32 KB
    unsigned short* Wt      = (unsigned short*)(ws + (2u << 20) + (2u << 15));  // 512 KB
    unsigned short* cbn_sT  = (unsigned short*)(ws + (3u << 20));       // 8 MB (swizzled, dinv_j-scaled)
    unsigned short* hbuf    = (unsigned short*)(ws + (11u << 20));      // 8 MB
    unsigned short* A_swz   = (unsigned short*)(ws + (19u << 20));      // 128 MB (swizzled adjacency)

    k_prep_bbn<<<2048, 256, 0, stream>>>(bbn, bbn_h, bbn_swz, s);
    k_zero_d<<<8, 1024, 0, stream>>>(dd);
    k_transpose_scale<<<64, 256, 0, stream>>>(W, Wt, nullptr, 512, 512, 0);
    k_gen_adj<<<256, 1024, 0, stream>>>(bbn_h, bbn_swz, s, A_swz, dd);
    k_transpose_scale<<<1024, 256, 0, stream>>>(cbn, cbn_sT, dd, 8192, 512, 1);
    k_spectral<<<256, 1024, 0, stream>>>(A_swz, dd, cbn_sT, hbuf);
    k_out<<<512, 512, 0, stream>>>(hbuf, Wt, b, out);
}